// Round 11
// baseline (336.511 us; speedup 1.0000x reference)
//
#include <hip/hip_runtime.h>
#include <math.h>

#define NS 65536
#define LAN 2048
#define FEA 128

constexpr float THRES = 0.0025f;
constexpr float FEPS  = 1e-12f;
constexpr int BM   = 32;   // rows per block
constexpr int MAXS = 63;   // survivors/row cap; pack col-slot 63 holds cnt

typedef _Float16 half8 __attribute__((ext_vector_type(8)));
typedef float    f32x4 __attribute__((ext_vector_type(4)));

// ---- prep: blocks <1024: split W into f16 h/l; blocks >=1024: cen partial sums ----
__global__ void k_prep(const float* __restrict__ W,
                       _Float16* __restrict__ Wh, _Float16* __restrict__ Wl,
                       float* __restrict__ censum) {
    if (blockIdx.x < 1024) {
        int i = blockIdx.x * 256 + threadIdx.x;
        float w = W[i];
        _Float16 h = (_Float16)w;
        Wh[i] = h;
        Wl[i] = (_Float16)(w - (float)h);
    } else {
        __shared__ f32x4 sred[8][32];
        const int b = blockIdx.x - 1024;
        const int tid = threadIdx.x;
        const int rg = tid >> 5, q = tid & 31;
        const f32x4* W4 = (const f32x4*)W;
        f32x4 p = (f32x4){0.f, 0.f, 0.f, 0.f};
        #pragma unroll
        for (int j = 0; j < 8; ++j) {
            int row = b * 64 + rg * 8 + j;
            p += W4[(size_t)row * 32 + q];
        }
        sred[rg][q] = p;
        __syncthreads();
        if (tid < 32) {
            f32x4 s = sred[0][tid];
            #pragma unroll
            for (int w = 1; w < 8; ++w) s += sred[w][tid];
            #pragma unroll
            for (int e = 0; e < 4; ++e)
                atomicAdd(&censum[tid * 4 + e], s[e]);
        }
    }
}

__device__ static inline void gload_lds16(const void* g, void* l) {
    __builtin_amdgcn_global_load_lds(
        (const __attribute__((address_space(1))) void*)g,
        (__attribute__((address_space(3))) void*)l, 16, 0, 0);
}

// ---- main kernel: GEMM + softmax/shrink + packed survivor lists + col ----
// 512 threads = 8 waves = 4 pairs. Pair p owns cols [512p, 512p+512); wave rt=wv&1
// takes rows rt*16..rt*16+15. Per step (32 steps of 16 cols): one shared 8KB tile
// per pair (h-half DMA'd by rt=0 wave, l-half by rt=1 wave) in a 4-slot ring ->
// 3 tiles in flight. Discipline per step: wait OWN vmcnt -> s_barrier (all waves'
// shares of tile t now visible) -> issue tile t+3 (slot (t+3)&3 == (t-1)&3, whose
// readers all drained before barrier t) -> ds_read -> MFMA -> fused exp.
// MFMA 16x16x32_f16, 3-term split. C-frag: row=rt*16+(lane>>4)*4+r, col=lane&15.
__global__ __launch_bounds__(512, 2) void k_main(
    const float* __restrict__ X,
    const _Float16* __restrict__ Wh, const _Float16* __restrict__ Wl,
    const float* __restrict__ censum,
    float* __restrict__ o_att, float* __restrict__ o_col)
{
    // [0,128K): 4-slot tile ring (slot: 4 pairs x (4K h + 4K l)); [128K,144K): X tile
    // post-GEMM overlay: s_scol @0 (8K), s_sval @16K (8K)
    __shared__ __align__(16) char s_pool[147456];
    __shared__ float s_red[8][BM];
    __shared__ float s_rsinv[BM], s_Sinv[BM];
    __shared__ int   s_cnt[BM];

    const int tid  = threadIdx.x;
    const int wv   = tid >> 6;
    const int lane = tid & 63;
    const int g    = lane >> 4;
    const int m    = lane & 15;
    const int pair = wv >> 1;
    const int rt   = wv & 1;
    const int row0 = blockIdx.x * BM;
    constexpr int XOFF = 131072;

    // wave issues its half (h if rt=0, l if rt=1) of its pair's tile t_ into slot_
    #define ISSUE_T(t_, slot_)                                                     \
        {                                                                          \
            const char* gsrc_ = (const char*)((rt ? Wl : Wh) +                     \
                                 (size_t)(pair * 512 + (t_) * 16) * FEA);          \
            char* lb_ = s_pool + (slot_) * 32768 + pair * 8192 + rt * 4096;        \
            _Pragma("unroll")                                                      \
            for (int i_ = 0; i_ < 4; ++i_) {                                       \
                int c_ = i_ * 64 + lane;                                           \
                int gc_ = c_ ^ ((c_ >> 4) & 7);                                    \
                gload_lds16(gsrc_ + gc_ * 16, lb_ + i_ * 1024);                    \
            }                                                                      \
        }

    // ---- prologue: X DMA (2 insts/wave), then tiles 0,1,2 (4 insts/wave each) ----
    {
        const char* xg = (const char*)(X + (size_t)row0 * FEA);
        gload_lds16(xg + (wv * 2 + 0) * 1024 + lane * 16, s_pool + XOFF + (wv * 2 + 0) * 1024);
        gload_lds16(xg + (wv * 2 + 1) * 1024 + lane * 16, s_pool + XOFF + (wv * 2 + 1) * 1024);
    }
    ISSUE_T(0, 0) ISSUE_T(1, 1) ISSUE_T(2, 2)
    asm volatile("s_waitcnt vmcnt(12)" ::: "memory");   // own X (oldest 2) landed
    __builtin_amdgcn_s_barrier();                       // all waves' X visible
    __builtin_amdgcn_sched_barrier(0);

    // ---- A fragments (f16 split) for THIS wave's 16 rows ----
    half8 afh[4], afl[4];
    #pragma unroll
    for (int kb = 0; kb < 4; ++kb) {
        const char* base = s_pool + XOFF + (rt * 16 + m) * 512 + (kb * 8 + g * 2) * 16;
        f32x4 xa = *(const f32x4*)(base);
        f32x4 xb = *(const f32x4*)(base + 16);
        half8 h, l;
        #pragma unroll
        for (int e = 0; e < 4; ++e) {
            _Float16 hh = (_Float16)xa[e];
            h[e] = hh; l[e] = (_Float16)(xa[e] - (float)hh);
        }
        #pragma unroll
        for (int e = 0; e < 4; ++e) {
            _Float16 hh = (_Float16)xb[e];
            h[4 + e] = hh; l[4 + e] = (_Float16)(xb[e] - (float)hh);
        }
        afh[kb] = h; afl[kb] = l;
    }

    // ---- col mask from X tile (wave wv: rows wv*4..+3) ----
    const float inv2048 = 1.0f / 2048.0f;
    #pragma unroll
    for (int u = 0; u < 4; ++u) {
        const int lr = wv * 4 + u;
        float2 x2 = *(const float2*)(s_pool + XOFF + lr * 512 + lane * 8);
        float dx0 = x2.x - censum[lane * 2] * inv2048;
        float dx1 = x2.y - censum[lane * 2 + 1] * inv2048;
        float dd = dx0 * dx0 + dx1 * dx1;
        #pragma unroll
        for (int off = 32; off >= 1; off >>= 1) dd += __shfl_xor(dd, off);
        if (lane == 0) o_col[row0 + lr] = (sqrtf(dd) < 1.0f) ? 1.0f : 0.0f;
    }

    f32x4 acc[32];
    #pragma unroll
    for (int t = 0; t < 32; ++t) acc[t] = (f32x4){0.f, 0.f, 0.f, 0.f};
    float ssum[4] = {0.f, 0.f, 0.f, 0.f};

    // ---- GEMM: 32 col-steps, 4-slot ring, 3 tiles in flight ----
    #pragma unroll 32
    for (int t = 0; t < 32; ++t) {
        // own outstanding: tiles t..min(t+2,31) x 4 insts; wait for tile t
        if (t <= 29)      { asm volatile("s_waitcnt vmcnt(8)" ::: "memory"); }
        else if (t == 30) { asm volatile("s_waitcnt vmcnt(4)" ::: "memory"); }
        else              { asm volatile("s_waitcnt vmcnt(0)" ::: "memory"); }
        __builtin_amdgcn_sched_barrier(0);
        __builtin_amdgcn_s_barrier();          // tile t fully visible; slot (t-1)&3 drained
        __builtin_amdgcn_sched_barrier(0);
        if (t < 29) ISSUE_T(t + 3, (t + 3) & 3)
        const char* bb = s_pool + (t & 3) * 32768 + pair * 8192;
        half8 bh[4], bl[4];
        #pragma unroll
        for (int kb = 0; kb < 4; ++kb) {
            int off = (m * 256 + kb * 64 + g * 16) ^ ((m & 7) << 4);
            bh[kb] = *(const half8*)(bb + off);
            bl[kb] = *(const half8*)(bb + 4096 + off);
        }
        asm volatile("s_waitcnt lgkmcnt(0)" ::: "memory");
        __builtin_amdgcn_sched_barrier(0);
        __builtin_amdgcn_s_setprio(1);
        #pragma unroll
        for (int kb = 0; kb < 4; ++kb) {
            acc[t] = __builtin_amdgcn_mfma_f32_16x16x32_f16(afh[kb], bh[kb], acc[t], 0, 0, 0);
            acc[t] = __builtin_amdgcn_mfma_f32_16x16x32_f16(afl[kb], bh[kb], acc[t], 0, 0, 0);
            acc[t] = __builtin_amdgcn_mfma_f32_16x16x32_f16(afh[kb], bl[kb], acc[t], 0, 0, 0);
        }
        __builtin_amdgcn_s_setprio(0);
        // fused exp + running row sum (acc[t] final after this step)
        #pragma unroll
        for (int r = 0; r < 4; ++r) {
            float e = __expf(acc[t][r]);
            acc[t][r] = e;
            ssum[r] += e;
        }
    }
    #undef ISSUE_T

    // lane's row for r: lr = rt*16 + g*4 + r ; col for t: pair*512 + t*16 + m

    // ---- P1: row-sum reduce (4 pairs contribute per row) ----
    #pragma unroll
    for (int r = 0; r < 4; ++r) {
        float s = ssum[r];
        #pragma unroll
        for (int off = 8; off >= 1; off >>= 1) s += __shfl_xor(s, off);
        if (m == 0) s_red[wv][rt * 16 + g * 4 + r] = s;
    }
    __syncthreads();
    if (tid < BM) {
        const int b = tid >> 4;   // rt of this row
        float s = s_red[b][tid] + s_red[b + 2][tid] + s_red[b + 4][tid] + s_red[b + 6][tid];
        s_rsinv[tid] = 1.0f / s;  // sum >= 1 always
        s_cnt[tid] = 0;
    }
    __syncthreads();

    // ---- P2: survivor scan (exact shrink arithmetic), unnormalized vals + S ----
    int*   s_scol = (int*)s_pool;              // [32][64] (ring dead)
    float* s_sval = (float*)(s_pool + 16384);  // [32][64]
    #pragma unroll
    for (int r = 0; r < 4; ++r) {
        const int lr = rt * 16 + g * 4 + r;
        const float ri = s_rsinv[lr];
        float S = 0.f;
        #pragma unroll
        for (int t = 0; t < 32; ++t) {
            float soft = acc[t][r] * ri;
            float sh = soft - THRES;
            if (sh > 0.f) {
                float v = sh * soft / (sh + FEPS);
                S += v;
                int p = atomicAdd(&s_cnt[lr], 1);
                if (p < MAXS) { s_scol[lr * 64 + p] = pair * 512 + t * 16 + m; s_sval[lr * 64 + p] = v; }
            }
        }
        #pragma unroll
        for (int off = 8; off >= 1; off >>= 1) S += __shfl_xor(S, off);
        if (m == 0) s_red[wv][lr] = S;
    }
    __syncthreads();
    if (tid < BM) {
        const int b = tid >> 4;
        float S = s_red[b][tid] + s_red[b + 2][tid] + s_red[b + 4][tid] + s_red[b + 6][tid];
        s_Sinv[tid] = 1.0f / fmaxf(S, FEPS);
    }
    __syncthreads();

    // ---- pack to o_att row head: [64 vals (normalized) | 63 cols | cnt] ----
    {
        const int lrp = tid >> 4, j = tid & 15;     // 16 threads/row
        const int cn = min(s_cnt[lrp], MAXS);
        const float si = s_Sinv[lrp];
        f32x4 vq, cq;
        #pragma unroll
        for (int e = 0; e < 4; ++e) {
            int p = j * 4 + e;
            if (p == 63) {
                vq[e] = 0.f;
                cq[e] = __int_as_float(cn);
            } else {
                bool live = p < cn;
                vq[e] = live ? s_sval[lrp * 64 + p] * si : 0.f;
                cq[e] = __int_as_float(live ? s_scol[lrp * 64 + p] : 0);
            }
        }
        float* base = o_att + (size_t)(row0 + lrp) * LAN;
        *(f32x4*)(base + j * 4)      = vq;
        *(f32x4*)(base + 64 + j * 4) = cq;
    }
}

// ---- expander + finals: 8 rows/block; LDS-compose att, top-2, out/nl/nl2 ----
__global__ __launch_bounds__(256) void k_att(
    const float* __restrict__ W,
    float* __restrict__ o_att, float* __restrict__ o_out,
    float* __restrict__ o_nl, float* __restrict__ o_nl2)
{
    __shared__ float s_att[8 * 2048];      // 64 KB
    __shared__ float s_pack[8][128];       // 4 KB
    __shared__ int   s_i1[8], s_i2[8];

    const int tid = threadIdx.x;
    const size_t rows0 = (size_t)blockIdx.x * 8;
    const int row = tid >> 5, q = tid & 31;

    *(f32x4*)&s_pack[row][q * 4] = *(const f32x4*)(o_att + (rows0 + row) * LAN + q * 4);
    __syncthreads();

    if (tid < 8) {
        const float* pk = s_pack[tid];
        const int cnt = __float_as_int(pk[64 + 63]);
        float t1v = -1.f, t2v = -1.f; int t1c = 0x7fffffff, t2c = 0x7fffffff;
        for (int p = 0; p < cnt; ++p) {
            float v = pk[p]; int c = __float_as_int(pk[64 + p]);
            if (v > t1v || (v == t1v && c < t1c)) {
                t2v = t1v; t2c = t1c; t1v = v; t1c = c;
            } else if (v > t2v || (v == t2v && c < t2c)) {
                t2v = v; t2c = c;
            }
        }
        s_i1[tid] = (cnt >= 1) ? t1c : 0;
        s_i2[tid] = (cnt >= 2) ? t2c : 0;
    }
    f32x4* sa4 = (f32x4*)s_att;
    #pragma unroll
    for (int e = 0; e < 16; ++e) sa4[e * 256 + tid] = (f32x4){0.f, 0.f, 0.f, 0.f};
    __syncthreads();

    {
        const int cnt = __float_as_int(s_pack[row][64 + 63]);
        #pragma unroll
        for (int h = 0; h < 2; ++h) {
            int p = q + h * 32;
            if (p < cnt) {
                float v = s_pack[row][p];
                int c = __float_as_int(s_pack[row][64 + p]);
                s_att[row * 2048 + c] = v;
            }
        }
        f32x4 o = (f32x4){0.f, 0.f, 0.f, 0.f};
        for (int p = 0; p < cnt; ++p) {
            float v = s_pack[row][p];
            int c = __float_as_int(s_pack[row][64 + p]);
            const f32x4 w4 = *(const f32x4*)(W + (size_t)c * FEA + q * 4);
            o += v * w4;
        }
        __builtin_nontemporal_store(o, (f32x4*)(o_out + (rows0 + row) * FEA + q * 4));
        const int i1 = s_i1[row], i2 = s_i2[row];
        __builtin_nontemporal_store(*(const f32x4*)(W + (size_t)i1 * FEA + q * 4),
                                    (f32x4*)(o_nl  + (rows0 + row) * FEA + q * 4));
        __builtin_nontemporal_store(*(const f32x4*)(W + (size_t)i2 * FEA + q * 4),
                                    (f32x4*)(o_nl2 + (rows0 + row) * FEA + q * 4));
    }
    __syncthreads();

    // stream dense att rows (nontemporal full-line f32x4)
    float* gdst = o_att + rows0 * LAN;
    #pragma unroll
    for (int e = 0; e < 16; ++e) {
        int fi = e * 256 + tid;
        __builtin_nontemporal_store(sa4[fi], (f32x4*)(gdst + (size_t)fi * 4));
    }
}

extern "C" void kernel_launch(void* const* d_in, const int* in_sizes, int n_in,
                              void* d_out, int out_size, void* d_ws, size_t ws_size,
                              hipStream_t stream) {
    const float* X = (const float*)d_in[0];
    const float* W = (const float*)d_in[1];

    _Float16* Wh = (_Float16*)d_ws;                       // 512 KB
    _Float16* Wl = Wh + (size_t)LAN * FEA;                // 512 KB
    float*    censum = (float*)(Wl + (size_t)LAN * FEA);  // 512 B

    float* out      = (float*)d_out;
    float* o_output = out;
    float* o_att    = o_output + (size_t)NS * FEA;
    float* o_nl     = o_att    + (size_t)NS * LAN;
    float* o_nl2    = o_nl     + (size_t)NS * FEA;
    float* o_col    = o_nl2    + (size_t)NS * FEA;

    hipMemsetAsync(censum, 0, FEA * sizeof(float), stream);
    k_prep<<<1056, 256, 0, stream>>>(W, Wh, Wl, censum);
    k_main<<<NS / BM, 512, 0, stream>>>(X, Wh, Wl, censum, o_att, o_col);
    k_att<<<NS / 8, 256, 0, stream>>>(W, o_att, o_output, o_nl, o_nl2);
}